// Round 1
// baseline (2654.438 us; speedup 1.0000x reference)
//
#include <hip/hip_runtime.h>
#include <hip/hip_bf16.h>

#define NB  2
#define SS  2048
#define HH  4096
#define NH  32
#define NKV 8
#define HD  128
#define MR  (NB*SS)   // 4096 token rows

typedef __bf16 bf16x8 __attribute__((ext_vector_type(8)));
typedef float  f32x4  __attribute__((ext_vector_type(4)));
using bf16 = __hip_bfloat16;

__device__ __forceinline__ f32x4 mfma16(bf16x8 a, bf16x8 b, f32x4 c) {
  return __builtin_amdgcn_mfma_f32_16x16x32_bf16(a, b, c, 0, 0, 0);
}

// ---------------------------------------------------------------- fp32 -> bf16
__global__ void f2b(const float* __restrict__ s, bf16* __restrict__ d, int n)
{
  int i = blockIdx.x*blockDim.x + threadIdx.x;
  int stride = gridDim.x*blockDim.x;
  for (int idx = i*4; idx < n; idx += stride*4) {
    float4 v = *(const float4*)(s + idx);
    __hip_bfloat16 b0 = __float2bfloat16(v.x);
    __hip_bfloat16 b1 = __float2bfloat16(v.y);
    __hip_bfloat16 b2 = __float2bfloat16(v.z);
    __hip_bfloat16 b3 = __float2bfloat16(v.w);
    ushort4 o;
    o.x = *reinterpret_cast<unsigned short*>(&b0);
    o.y = *reinterpret_cast<unsigned short*>(&b1);
    o.z = *reinterpret_cast<unsigned short*>(&b2);
    o.w = *reinterpret_cast<unsigned short*>(&b3);
    *(ushort4*)((unsigned short*)d + idx) = o;
  }
}

// ------------------------------------------------- C[M,N] = A[M,K] @ Bt[N,K]^T
// 128x128 tile, 4 waves (2x2), BK=64, mfma 16x16x32 bf16, reg-staged LDS.
template<typename OutT>
__global__ __launch_bounds__(256) void gemm_bt(
    const bf16* __restrict__ A, const bf16* __restrict__ Bt, OutT* __restrict__ C,
    int M, int N, int K)
{
  __shared__ bf16 As[128*64];
  __shared__ bf16 Bs[128*64];
  const int tid = threadIdx.x;
  const int w = tid >> 6, l = tid & 63;
  const int l15 = l & 15, lhi = l >> 4;
  const int m0 = blockIdx.y * 128, n0 = blockIdx.x * 128;
  const int wr = w >> 1, wc = w & 1;

  f32x4 acc[4][4];
  #pragma unroll
  for (int m = 0; m < 4; ++m)
    #pragma unroll
    for (int n = 0; n < 4; ++n)
      #pragma unroll
      for (int e = 0; e < 4; ++e) acc[m][n][e] = 0.f;

  const int srow = w*8 + (l >> 3);   // staging row within each 32-row group
  const int scol = (l & 7)*8;        // staging col (elements)

  for (int k0 = 0; k0 < K; k0 += 64) {
    float4 va[4], vb[4];
    #pragma unroll
    for (int i = 0; i < 4; ++i) {
      va[i] = *(const float4*)(A  + (size_t)(m0 + i*32 + srow)*K + k0 + scol);
      vb[i] = *(const float4*)(Bt + (size_t)(n0 + i*32 + srow)*K + k0 + scol);
    }
    __syncthreads();                 // prior compute done before LDS overwrite
    #pragma unroll
    for (int i = 0; i < 4; ++i) {
      *(float4*)&As[(i*32 + srow)*64 + scol] = va[i];
      *(float4*)&Bs[(i*32 + srow)*64 + scol] = vb[i];
    }
    __syncthreads();
    #pragma unroll
    for (int kk = 0; kk < 2; ++kk) {
      bf16x8 af[4], bfr[4];
      #pragma unroll
      for (int m = 0; m < 4; ++m)
        af[m] = *(const bf16x8*)&As[(wr*64 + m*16 + l15)*64 + kk*32 + lhi*8];
      #pragma unroll
      for (int n = 0; n < 4; ++n)
        bfr[n] = *(const bf16x8*)&Bs[(wc*64 + n*16 + l15)*64 + kk*32 + lhi*8];
      #pragma unroll
      for (int m = 0; m < 4; ++m)
        #pragma unroll
        for (int n = 0; n < 4; ++n)
          acc[m][n] = mfma16(af[m], bfr[n], acc[m][n]);
    }
  }

  #pragma unroll
  for (int m = 0; m < 4; ++m) {
    const int crow = m0 + wr*64 + m*16 + lhi*4;
    #pragma unroll
    for (int n = 0; n < 4; ++n) {
      const int ccol = n0 + wc*64 + n*16 + l15;
      #pragma unroll
      for (int j = 0; j < 4; ++j) {
        if constexpr (sizeof(OutT) == 2)
          C[(size_t)(crow + j)*N + ccol] = __float2bfloat16(acc[m][n][j]);
        else
          C[(size_t)(crow + j)*N + ccol] = acc[m][n][j];
      }
    }
  }
}

// ------------------------------------- RMSNorm(head of 128) + RoPE, relayout
// One wave per (b,s,head) row; lane t owns dims {t, t+64}.
__global__ __launch_bounds__(256) void normrope(
    const bf16* __restrict__ src, bf16* __restrict__ dst,
    const float* __restrict__ cosb, const float* __restrict__ sinb,
    const float* __restrict__ w, int nh, float scale)
{
  const int wid = threadIdx.x >> 6, lane = threadIdx.x & 63;
  const int row = blockIdx.x*4 + wid;
  const int m = row / nh, h = row % nh;     // m = b*S+s
  const int b = m / SS, s = m % SS;
  const bf16* sp = src + (size_t)m*nh*HD + h*HD;
  float v1 = __bfloat162float(sp[lane]);
  float v2 = __bfloat162float(sp[lane + 64]);
  float ss = v1*v1 + v2*v2;
  #pragma unroll
  for (int msk = 1; msk < 64; msk <<= 1) ss += __shfl_xor(ss, msk);
  float r = rsqrtf(ss*(1.f/128.f) + 1e-6f) * scale;
  float n1 = v1*r*w[lane], n2 = v2*r*w[lane + 64];
  const float* cp  = cosb + (size_t)m*HD;
  const float* sip = sinb + (size_t)m*HD;
  float o1 = n1*cp[lane]      - n2*sip[lane];
  float o2 = n2*cp[lane + 64] + n1*sip[lane + 64];
  bf16* dp = dst + ((size_t)(b*nh + h)*SS + s)*HD;
  dp[lane]      = __float2bfloat16(o1);
  dp[lane + 64] = __float2bfloat16(o2);
}

// --------------------------- v0[b,s,(kv,d)] -> vt[b,kv,d,s]  (LDS transpose)
__global__ __launch_bounds__(256) void vtrans(const bf16* __restrict__ v0,
                                              bf16* __restrict__ vt)
{
  __shared__ bf16 tile[64][65];
  const int s0 = blockIdx.x*64, d0 = blockIdx.y*64, bkv = blockIdx.z;
  const int bb = bkv >> 3, kv = bkv & 7;
  const int c = threadIdx.x & 63, rbase = threadIdx.x >> 6;
  #pragma unroll
  for (int r = 0; r < 64; r += 4) {
    int sl = r + rbase;
    tile[sl][c] = v0[(size_t)(bb*SS + s0 + sl)*(NKV*HD) + kv*HD + d0 + c];
  }
  __syncthreads();
  #pragma unroll
  for (int r = 0; r < 64; r += 4) {
    int dl = r + rbase;
    vt[((size_t)bkv*HD + d0 + dl)*SS + s0 + c] = tile[c][dl];
  }
}

// --------------------------------------------- causal GQA flash attention
// block = 4 waves; wave owns 16 q rows; KV tile = 64; scale pre-folded in q.
__global__ __launch_bounds__(256) void attn_fwd(
    const bf16* __restrict__ qr, const bf16* __restrict__ kr,
    const bf16* __restrict__ vt, bf16* __restrict__ ao)
{
  const int qtile = blockIdx.x, h = blockIdx.y, b = blockIdx.z;
  const int wid = threadIdx.x >> 6, lane = threadIdx.x & 63;
  const int l15 = lane & 15, lhi = lane >> 4;
  const int qw = qtile*64 + wid*16;
  const int kvh = h >> 2;                       // NH/NKV = 4
  const bf16* Q = qr + ((size_t)(b*NH + h)*SS + qw)*HD;
  const bf16* K = kr + ((size_t)(b*NKV + kvh)*SS)*HD;
  const bf16* V = vt + ((size_t)(b*NKV + kvh)*HD)*SS;   // [HD][S]

  __shared__ bf16 plds[4][16][64];

  bf16x8 qf[4];
  #pragma unroll
  for (int kk = 0; kk < 4; ++kk)
    qf[kk] = *(const bf16x8*)(Q + (size_t)l15*HD + kk*32 + lhi*8);

  f32x4 o[8];
  #pragma unroll
  for (int c = 0; c < 8; ++c)
    #pragma unroll
    for (int e = 0; e < 4; ++e) o[c][e] = 0.f;
  float mrow[4], lrow[4];
  #pragma unroll
  for (int j = 0; j < 4; ++j) { mrow[j] = -__builtin_inff(); lrow[j] = 0.f; }

  for (int t = 0; t <= qtile; ++t) {
    const int kv0 = t*64;
    f32x4 s4[4];
    #pragma unroll
    for (int c = 0; c < 4; ++c) {
      f32x4 a; a[0]=a[1]=a[2]=a[3]=0.f;
      #pragma unroll
      for (int kk = 0; kk < 4; ++kk) {
        bf16x8 kf = *(const bf16x8*)(K + (size_t)(kv0 + c*16 + l15)*HD + kk*32 + lhi*8);
        a = mfma16(qf[kk], kf, a);
      }
      s4[c] = a;
    }
    if (t == qtile) {                       // only diagonal tile needs masking
      #pragma unroll
      for (int c = 0; c < 4; ++c)
        #pragma unroll
        for (int j = 0; j < 4; ++j)
          if (kv0 + c*16 + l15 > qw + lhi*4 + j) s4[c][j] = -1e30f;
    }
    float alpha[4];
    #pragma unroll
    for (int j = 0; j < 4; ++j) {
      float tm = fmaxf(fmaxf(s4[0][j], s4[1][j]), fmaxf(s4[2][j], s4[3][j]));
      tm = fmaxf(tm, __shfl_xor(tm, 1));
      tm = fmaxf(tm, __shfl_xor(tm, 2));
      tm = fmaxf(tm, __shfl_xor(tm, 4));
      tm = fmaxf(tm, __shfl_xor(tm, 8));
      float mn = fmaxf(mrow[j], tm);
      alpha[j] = __expf(mrow[j] - mn);
      mrow[j] = mn;
    }
    float rsum[4] = {0.f, 0.f, 0.f, 0.f};
    #pragma unroll
    for (int c = 0; c < 4; ++c)
      #pragma unroll
      for (int j = 0; j < 4; ++j) {
        float p = __expf(s4[c][j] - mrow[j]);
        s4[c][j] = p;
        rsum[j] += p;
      }
    #pragma unroll
    for (int j = 0; j < 4; ++j) {
      float rs = rsum[j];
      rs += __shfl_xor(rs, 1);
      rs += __shfl_xor(rs, 2);
      rs += __shfl_xor(rs, 4);
      rs += __shfl_xor(rs, 8);
      lrow[j] = lrow[j]*alpha[j] + rs;
    }
    #pragma unroll
    for (int c = 0; c < 8; ++c)
      #pragma unroll
      for (int j = 0; j < 4; ++j) o[c][j] *= alpha[j];

    __syncthreads();                        // order prev PV reads vs new writes
    #pragma unroll
    for (int c = 0; c < 4; ++c)
      #pragma unroll
      for (int j = 0; j < 4; ++j)
        plds[wid][lhi*4 + j][c*16 + l15] = __float2bfloat16(s4[c][j]);
    __syncthreads();                        // writes ordered before reads

    #pragma unroll
    for (int ks = 0; ks < 2; ++ks) {
      bf16x8 pf = *(const bf16x8*)&plds[wid][l15][ks*32 + lhi*8];
      #pragma unroll
      for (int c2 = 0; c2 < 8; ++c2) {
        bf16x8 vf = *(const bf16x8*)(V + (size_t)(c2*16 + l15)*SS + kv0 + ks*32 + lhi*8);
        o[c2] = mfma16(pf, vf, o[c2]);
      }
    }
  }

  float inv[4];
  #pragma unroll
  for (int j = 0; j < 4; ++j) inv[j] = 1.f / lrow[j];
  bf16* aop = ao + ((size_t)b*SS + qw)*HH + h*HD;
  #pragma unroll
  for (int c2 = 0; c2 < 8; ++c2)
    #pragma unroll
    for (int j = 0; j < 4; ++j)
      aop[(size_t)(lhi*4 + j)*HH + c2*16 + l15] = __float2bfloat16(o[c2][j]*inv[j]);
}

// --------------------------------------------------------------------- launch
extern "C" void kernel_launch(void* const* d_in, const int* in_sizes, int n_in,
                              void* d_out, int out_size, void* d_ws, size_t ws_size,
                              hipStream_t stream)
{
  const float* x    = (const float*)d_in[0];
  const float* cosb = (const float*)d_in[1];
  const float* sinb = (const float*)d_in[2];
  const float* wq   = (const float*)d_in[3];
  const float* wk   = (const float*)d_in[4];
  const float* wv   = (const float*)d_in[5];
  const float* wo   = (const float*)d_in[6];
  const float* qnw  = (const float*)d_in[7];
  const float* knw  = (const float*)d_in[8];
  float* out = (float*)d_out;

  char* ws = (char*)d_ws;
  bf16* xb  = (bf16*)(ws);                  // 32 MiB
  bf16* wqb = (bf16*)(ws +  33554432);      // 32 MiB
  bf16* wkb = (bf16*)(ws +  67108864);      //  8 MiB
  bf16* wvb = (bf16*)(ws +  75497472);      //  8 MiB
  bf16* wob = (bf16*)(ws +  83886080);      // 32 MiB
  bf16* q0  = (bf16*)(ws + 117440512);      // 32 MiB
  bf16* k0  = (bf16*)(ws + 150994944);      //  8 MiB
  bf16* v0  = (bf16*)(ws + 159383552);      //  8 MiB
  bf16* qr  = (bf16*)(ws + 167772160);      // 32 MiB  (end 192 MiB)
  // ordering-safe aliases:
  bf16* vt = xb;    // xb dead after QKV GEMMs
  bf16* kr = wqb;   // wqb dead after Q GEMM
  bf16* ao = q0;    // q0 dead after q normrope

  f2b<<<2048, 256, 0, stream>>>(x,  xb,  MR*HH);
  f2b<<<2048, 256, 0, stream>>>(wq, wqb, NH*HD*HH);
  f2b<<<2048, 256, 0, stream>>>(wk, wkb, NKV*HD*HH);
  f2b<<<2048, 256, 0, stream>>>(wv, wvb, NKV*HD*HH);
  f2b<<<2048, 256, 0, stream>>>(wo, wob, HH*NH*HD);

  gemm_bt<bf16><<<dim3(32, 32), 256, 0, stream>>>(xb, wqb, q0, MR, 4096, HH);
  gemm_bt<bf16><<<dim3( 8, 32), 256, 0, stream>>>(xb, wkb, k0, MR, 1024, HH);
  gemm_bt<bf16><<<dim3( 8, 32), 256, 0, stream>>>(xb, wvb, v0, MR, 1024, HH);

  normrope<<<(MR*NH)/4,  256, 0, stream>>>(q0, qr, cosb, sinb, qnw, NH, 0.08838834764831845f);
  normrope<<<(MR*NKV)/4, 256, 0, stream>>>(k0, kr, cosb, sinb, knw, NKV, 1.0f);
  vtrans<<<dim3(32, 2, 16), 256, 0, stream>>>(v0, vt);

  attn_fwd<<<dim3(32, 32, 2), 256, 0, stream>>>(qr, kr, vt, ao);

  gemm_bt<float><<<dim3(32, 32), 256, 0, stream>>>(ao, wob, out, MR, HH, HH);
}

// Round 2
// 1258.096 us; speedup vs baseline: 2.1099x; 2.1099x over previous
//
#include <hip/hip_runtime.h>
#include <hip/hip_bf16.h>

#define NB  2
#define SS  2048
#define HH  4096
#define NH  32
#define NKV 8
#define HD  128
#define MR  (NB*SS)   // 4096 token rows

typedef __bf16 bf16x8 __attribute__((ext_vector_type(8)));
typedef float  f32x4  __attribute__((ext_vector_type(4)));
using bf16 = __hip_bfloat16;

__device__ __forceinline__ f32x4 mfma16(bf16x8 a, bf16x8 b, f32x4 c) {
  return __builtin_amdgcn_mfma_f32_16x16x32_bf16(a, b, c, 0, 0, 0);
}

typedef const __attribute__((address_space(1))) void gv_t;
typedef __attribute__((address_space(3))) void lv_t;
__device__ __forceinline__ void gload16(const void* g, void* l) {
  __builtin_amdgcn_global_load_lds((gv_t*)g, (lv_t*)l, 16, 0, 0);
}

// ---------------------------------------------------------------- fp32 -> bf16
__global__ void f2b(const float* __restrict__ s, bf16* __restrict__ d, int n)
{
  int i = blockIdx.x*blockDim.x + threadIdx.x;
  int stride = gridDim.x*blockDim.x;
  for (int idx = i*4; idx < n; idx += stride*4) {
    float4 v = *(const float4*)(s + idx);
    __hip_bfloat16 b0 = __float2bfloat16(v.x);
    __hip_bfloat16 b1 = __float2bfloat16(v.y);
    __hip_bfloat16 b2 = __float2bfloat16(v.z);
    __hip_bfloat16 b3 = __float2bfloat16(v.w);
    ushort4 o;
    o.x = *reinterpret_cast<unsigned short*>(&b0);
    o.y = *reinterpret_cast<unsigned short*>(&b1);
    o.z = *reinterpret_cast<unsigned short*>(&b2);
    o.w = *reinterpret_cast<unsigned short*>(&b3);
    *(ushort4*)((unsigned short*)d + idx) = o;
  }
}

// ------------------------------------------------- C[M,N] = A[M,K] @ Bt[N,K]^T
// m97 structure: 128x128 tile, 4 waves (2x2), BK=64, global_load_lds width=16.
template<typename OutT>
__global__ __launch_bounds__(256) void gemm_bt(
    const bf16* __restrict__ A, const bf16* __restrict__ Bt, OutT* __restrict__ C,
    int M, int N, int K)
{
  __shared__ bf16 As[128*64];
  __shared__ bf16 Bs[128*64];
  const int tid = threadIdx.x;
  const int w = tid >> 6, l = tid & 63;
  const int l15 = l & 15, lhi = l >> 4;
  const int m0 = blockIdx.y * 128, n0 = blockIdx.x * 128;
  const int wr = w >> 1, wc = w & 1;

  f32x4 acc[4][4];
  #pragma unroll
  for (int m = 0; m < 4; ++m)
    #pragma unroll
    for (int n = 0; n < 4; ++n)
      #pragma unroll
      for (int e = 0; e < 4; ++e) acc[m][n][e] = 0.f;

  const int srow = l >> 3;        // 0..7 row within 8-row chunk
  const int scol = (l & 7)*8;     // 0..56 col elements

  for (int k0 = 0; k0 < K; k0 += 64) {
    __syncthreads();                 // prior compute done before LDS overwrite
    #pragma unroll
    for (int i = 0; i < 4; ++i) {
      const int ci = w*4 + i;        // chunk 0..15, 8 rows each
      const int r = ci*8 + srow;
      gload16(A  + (size_t)(m0 + r)*K + k0 + scol, &As[r*64 + scol]);
      gload16(Bt + (size_t)(n0 + r)*K + k0 + scol, &Bs[r*64 + scol]);
    }
    __syncthreads();                 // compiler drains vmcnt before barrier
    #pragma unroll
    for (int kk = 0; kk < 2; ++kk) {
      bf16x8 af[4], bfr[4];
      #pragma unroll
      for (int m = 0; m < 4; ++m)
        af[m] = *(const bf16x8*)&As[(wr*64 + m*16 + l15)*64 + kk*32 + lhi*8];
      #pragma unroll
      for (int n = 0; n < 4; ++n)
        bfr[n] = *(const bf16x8*)&Bs[(wc*64 + n*16 + l15)*64 + kk*32 + lhi*8];
      #pragma unroll
      for (int m = 0; m < 4; ++m)
        #pragma unroll
        for (int n = 0; n < 4; ++n)
          acc[m][n] = mfma16(af[m], bfr[n], acc[m][n]);
    }
  }

  #pragma unroll
  for (int m = 0; m < 4; ++m) {
    const int crow = m0 + wr*64 + m*16 + lhi*4;
    #pragma unroll
    for (int n = 0; n < 4; ++n) {
      const int ccol = n0 + wc*64 + n*16 + l15;
      #pragma unroll
      for (int j = 0; j < 4; ++j) {
        if constexpr (sizeof(OutT) == 2)
          C[(size_t)(crow + j)*N + ccol] = __float2bfloat16(acc[m][n][j]);
        else
          C[(size_t)(crow + j)*N + ccol] = acc[m][n][j];
      }
    }
  }
}

// ------------------------------------- RMSNorm(head of 128) + RoPE, relayout
__global__ __launch_bounds__(256) void normrope(
    const bf16* __restrict__ src, bf16* __restrict__ dst,
    const float* __restrict__ cosb, const float* __restrict__ sinb,
    const float* __restrict__ w, int nh, float scale)
{
  const int wid = threadIdx.x >> 6, lane = threadIdx.x & 63;
  const int row = blockIdx.x*4 + wid;
  const int m = row / nh, h = row % nh;     // m = b*S+s
  const int b = m / SS, s = m % SS;
  const bf16* sp = src + (size_t)m*nh*HD + h*HD;
  float v1 = __bfloat162float(sp[lane]);
  float v2 = __bfloat162float(sp[lane + 64]);
  float ss = v1*v1 + v2*v2;
  #pragma unroll
  for (int msk = 1; msk < 64; msk <<= 1) ss += __shfl_xor(ss, msk);
  float r = rsqrtf(ss*(1.f/128.f) + 1e-6f) * scale;
  float n1 = v1*r*w[lane], n2 = v2*r*w[lane + 64];
  const float* cp  = cosb + (size_t)m*HD;
  const float* sip = sinb + (size_t)m*HD;
  float o1 = n1*cp[lane]      - n2*sip[lane];
  float o2 = n2*cp[lane + 64] + n1*sip[lane + 64];
  bf16* dp = dst + ((size_t)(b*nh + h)*SS + s)*HD;
  dp[lane]      = __float2bfloat16(o1);
  dp[lane + 64] = __float2bfloat16(o2);
}

// --------------------------- v0[b,s,(kv,d)] -> vt[b,kv,d,s]  (LDS transpose)
__global__ __launch_bounds__(256) void vtrans(const bf16* __restrict__ v0,
                                              bf16* __restrict__ vt)
{
  __shared__ bf16 tile[64][65];
  const int s0 = blockIdx.x*64, d0 = blockIdx.y*64, bkv = blockIdx.z;
  const int bb = bkv >> 3, kv = bkv & 7;
  const int c = threadIdx.x & 63, rbase = threadIdx.x >> 6;
  #pragma unroll
  for (int r = 0; r < 64; r += 4) {
    int sl = r + rbase;
    tile[sl][c] = v0[(size_t)(bb*SS + s0 + sl)*(NKV*HD) + kv*HD + d0 + c];
  }
  __syncthreads();
  #pragma unroll
  for (int r = 0; r < 64; r += 4) {
    int dl = r + rbase;
    vt[((size_t)bkv*HD + d0 + dl)*SS + s0 + c] = tile[c][dl];
  }
}

// --------------------------------------------- causal GQA flash attention
// 4 waves/block, 16 q-rows/wave, KV tile 64. K/V cooperatively staged in
// padded LDS (2-way-max bank aliasing), T14 async prefetch of next tile.
__global__ __launch_bounds__(256, 3) void attn_fwd(
    const bf16* __restrict__ qr, const bf16* __restrict__ kr,
    const bf16* __restrict__ vt, bf16* __restrict__ ao)
{
  __shared__ bf16 Ks[64*136];        // [kv][128+8pad]
  __shared__ bf16 Vs[128*72];        // [d][64+8pad]
  __shared__ bf16 plds[4][16*72];    // per-wave P tile, padded

  const int qtile = blockIdx.x, h = blockIdx.y, b = blockIdx.z;
  const int wid = threadIdx.x >> 6, lane = threadIdx.x & 63;
  const int l15 = lane & 15, lhi = lane >> 4;
  const int qw = qtile*64 + wid*16;
  const int kvh = h >> 2;                       // NH/NKV = 4
  const bf16* Q = qr + ((size_t)(b*NH + h)*SS + qw)*HD;
  const bf16* K = kr + ((size_t)(b*NKV + kvh)*SS)*HD;
  const bf16* V = vt + ((size_t)(b*NKV + kvh)*HD)*SS;   // [HD][S]
  bf16* pl = plds[wid];

  // staging geometry (per wave: 4 K chunks of 4 rows, 4 V chunks of 8 rows)
  const int krw = lane >> 4;          // 0..3 row-in-chunk
  const int kcl = (lane & 15)*8;      // col elems (16 lanes = full 128-row)
  const int vrw = lane >> 3;          // 0..7 row-in-chunk
  const int vcl = (lane & 7)*8;       // col elems (8 lanes = full 64-row)

  bf16x8 qf[4];
  #pragma unroll
  for (int kk = 0; kk < 4; ++kk)
    qf[kk] = *(const bf16x8*)(Q + (size_t)l15*HD + kk*32 + lhi*8);

  float4 kreg[4], vreg[4];
  #pragma unroll
  for (int i = 0; i < 4; ++i) {
    kreg[i] = *(const float4*)(K + (size_t)((wid*4+i)*4 + krw)*HD + kcl);
    vreg[i] = *(const float4*)(V + (size_t)((wid*4+i)*8 + vrw)*SS + vcl);
  }
  #pragma unroll
  for (int i = 0; i < 4; ++i) {
    *(float4*)&Ks[((wid*4+i)*4 + krw)*136 + kcl] = kreg[i];
    *(float4*)&Vs[((wid*4+i)*8 + vrw)*72  + vcl] = vreg[i];
  }
  __syncthreads();

  f32x4 o[8];
  #pragma unroll
  for (int c = 0; c < 8; ++c)
    #pragma unroll
    for (int e = 0; e < 4; ++e) o[c][e] = 0.f;
  float mrow[4], lrow[4];
  #pragma unroll
  for (int j = 0; j < 4; ++j) { mrow[j] = -__builtin_inff(); lrow[j] = 0.f; }

  for (int t = 0; t <= qtile; ++t) {
    const int kv0 = t*64;
    if (t < qtile) {                    // async prefetch next tile into regs
      const int nv0 = kv0 + 64;
      #pragma unroll
      for (int i = 0; i < 4; ++i) {
        kreg[i] = *(const float4*)(K + (size_t)(nv0 + (wid*4+i)*4 + krw)*HD + kcl);
        vreg[i] = *(const float4*)(V + (size_t)((wid*4+i)*8 + vrw)*SS + nv0 + vcl);
      }
    }

    f32x4 s4[4];
    #pragma unroll
    for (int c = 0; c < 4; ++c) {
      f32x4 a; a[0]=a[1]=a[2]=a[3]=0.f;
      #pragma unroll
      for (int kk = 0; kk < 4; ++kk) {
        bf16x8 kf = *(const bf16x8*)&Ks[(c*16 + l15)*136 + kk*32 + lhi*8];
        a = mfma16(qf[kk], kf, a);
      }
      s4[c] = a;
    }
    if (t == qtile) {                   // only diagonal tile needs masking
      #pragma unroll
      for (int c = 0; c < 4; ++c)
        #pragma unroll
        for (int j = 0; j < 4; ++j)
          if (kv0 + c*16 + l15 > qw + lhi*4 + j) s4[c][j] = -1e30f;
    }
    float alpha[4];
    #pragma unroll
    for (int j = 0; j < 4; ++j) {
      float tm = fmaxf(fmaxf(s4[0][j], s4[1][j]), fmaxf(s4[2][j], s4[3][j]));
      tm = fmaxf(tm, __shfl_xor(tm, 1));
      tm = fmaxf(tm, __shfl_xor(tm, 2));
      tm = fmaxf(tm, __shfl_xor(tm, 4));
      tm = fmaxf(tm, __shfl_xor(tm, 8));
      float mn = fmaxf(mrow[j], tm);
      alpha[j] = __expf(mrow[j] - mn);
      mrow[j] = mn;
    }
    float rsum[4] = {0.f, 0.f, 0.f, 0.f};
    #pragma unroll
    for (int c = 0; c < 4; ++c)
      #pragma unroll
      for (int j = 0; j < 4; ++j) {
        float p = __expf(s4[c][j] - mrow[j]);
        s4[c][j] = p;
        rsum[j] += p;
      }
    #pragma unroll
    for (int j = 0; j < 4; ++j) {
      float rs = rsum[j];
      rs += __shfl_xor(rs, 1);
      rs += __shfl_xor(rs, 2);
      rs += __shfl_xor(rs, 4);
      rs += __shfl_xor(rs, 8);
      lrow[j] = lrow[j]*alpha[j] + rs;
    }
    #pragma unroll
    for (int c = 0; c < 8; ++c)
      #pragma unroll
      for (int j = 0; j < 4; ++j) o[c][j] *= alpha[j];

    // P through wave-private LDS (no cross-wave barrier needed; padded +8)
    #pragma unroll
    for (int c = 0; c < 4; ++c)
      #pragma unroll
      for (int j = 0; j < 4; ++j)
        pl[(lhi*4 + j)*72 + c*16 + l15] = __float2bfloat16(s4[c][j]);

    #pragma unroll
    for (int ks = 0; ks < 2; ++ks) {
      bf16x8 pf = *(const bf16x8*)&pl[l15*72 + ks*32 + lhi*8];
      #pragma unroll
      for (int c2 = 0; c2 < 8; ++c2) {
        bf16x8 vf = *(const bf16x8*)&Vs[(c2*16 + l15)*72 + ks*32 + lhi*8];
        o[c2] = mfma16(pf, vf, o[c2]);
      }
    }

    __syncthreads();                    // all waves done reading Ks/Vs
    if (t < qtile) {
      #pragma unroll
      for (int i = 0; i < 4; ++i) {
        *(float4*)&Ks[((wid*4+i)*4 + krw)*136 + kcl] = kreg[i];
        *(float4*)&Vs[((wid*4+i)*8 + vrw)*72  + vcl] = vreg[i];
      }
    }
    __syncthreads();                    // staged tile visible
  }

  float inv[4];
  #pragma unroll
  for (int j = 0; j < 4; ++j) inv[j] = 1.f / lrow[j];
  bf16* aop = ao + ((size_t)b*SS + qw)*HH + h*HD;
  #pragma unroll
  for (int c2 = 0; c2 < 8; ++c2)
    #pragma unroll
    for (int j = 0; j < 4; ++j)
      aop[(size_t)(lhi*4 + j)*HH + c2*16 + l15] = __float2bfloat16(o[c2][j]*inv[j]);
}

// --------------------------------------------------------------------- launch
extern "C" void kernel_launch(void* const* d_in, const int* in_sizes, int n_in,
                              void* d_out, int out_size, void* d_ws, size_t ws_size,
                              hipStream_t stream)
{
  const float* x    = (const float*)d_in[0];
  const float* cosb = (const float*)d_in[1];
  const float* sinb = (const float*)d_in[2];
  const float* wq   = (const float*)d_in[3];
  const float* wk   = (const float*)d_in[4];
  const float* wv   = (const float*)d_in[5];
  const float* wo   = (const float*)d_in[6];
  const float* qnw  = (const float*)d_in[7];
  const float* knw  = (const float*)d_in[8];
  float* out = (float*)d_out;

  char* ws = (char*)d_ws;
  bf16* xb  = (bf16*)(ws);                  // 32 MiB
  bf16* wqb = (bf16*)(ws +  33554432);      // 32 MiB
  bf16* wkb = (bf16*)(ws +  67108864);      //  8 MiB
  bf16* wvb = (bf16*)(ws +  75497472);      //  8 MiB
  bf16* wob = (bf16*)(ws +  83886080);      // 32 MiB
  bf16* q0  = (bf16*)(ws + 117440512);      // 32 MiB
  bf16* k0  = (bf16*)(ws + 150994944);      //  8 MiB
  bf16* v0  = (bf16*)(ws + 159383552);      //  8 MiB
  bf16* qr  = (bf16*)(ws + 167772160);      // 32 MiB  (end 192 MiB)
  // ordering-safe aliases:
  bf16* vt = xb;    // xb dead after QKV GEMMs
  bf16* kr = wqb;   // wqb dead after Q GEMM
  bf16* ao = q0;    // q0 dead after q normrope

  f2b<<<2048, 256, 0, stream>>>(x,  xb,  MR*HH);
  f2b<<<2048, 256, 0, stream>>>(wq, wqb, NH*HD*HH);
  f2b<<<2048, 256, 0, stream>>>(wk, wkb, NKV*HD*HH);
  f2b<<<2048, 256, 0, stream>>>(wv, wvb, NKV*HD*HH);
  f2b<<<2048, 256, 0, stream>>>(wo, wob, HH*NH*HD);

  gemm_bt<bf16><<<dim3(32, 32), 256, 0, stream>>>(xb, wqb, q0, MR, 4096, HH);
  gemm_bt<bf16><<<dim3( 8, 32), 256, 0, stream>>>(xb, wkb, k0, MR, 1024, HH);
  gemm_bt<bf16><<<dim3( 8, 32), 256, 0, stream>>>(xb, wvb, v0, MR, 1024, HH);

  normrope<<<(MR*NH)/4,  256, 0, stream>>>(q0, qr, cosb, sinb, qnw, NH, 0.08838834764831845f);
  normrope<<<(MR*NKV)/4, 256, 0, stream>>>(k0, kr, cosb, sinb, knw, NKV, 1.0f);
  vtrans<<<dim3(32, 2, 16), 256, 0, stream>>>(v0, vt);

  attn_fwd<<<dim3(32, 32, 2), 256, 0, stream>>>(qr, kr, vt, ao);

  gemm_bt<float><<<dim3(32, 32), 256, 0, stream>>>(ao, wob, out, MR, HH, HH);
}

// Round 3
// 770.101 us; speedup vs baseline: 3.4469x; 1.6337x over previous
//
#include <hip/hip_runtime.h>
#include <hip/hip_bf16.h>

#define NB  2
#define SS  2048
#define HH  4096
#define NH  32
#define NKV 8
#define HD  128
#define MR  (NB*SS)   // 4096 token rows

typedef __bf16 bf16x8 __attribute__((ext_vector_type(8)));
typedef float  f32x4  __attribute__((ext_vector_type(4)));
typedef float  f32x16 __attribute__((ext_vector_type(16)));
using bf16 = __hip_bfloat16;

__device__ __forceinline__ f32x4 mfma16(bf16x8 a, bf16x8 b, f32x4 c) {
  return __builtin_amdgcn_mfma_f32_16x16x32_bf16(a, b, c, 0, 0, 0);
}
__device__ __forceinline__ f32x16 mfma32(bf16x8 a, bf16x8 b, f32x16 c) {
  return __builtin_amdgcn_mfma_f32_32x32x16_bf16(a, b, c, 0, 0, 0);
}
__device__ __forceinline__ unsigned cvtpk(float lo, float hi) {
  unsigned r; asm("v_cvt_pk_bf16_f32 %0, %1, %2" : "=v"(r) : "v"(lo), "v"(hi));
  return r;
}
// exchanges a.hi-lanes <-> b.lo-lanes:  a' = [a.lo | b<-from-lane-32], b' = [a->from-lane+32 | b.hi]
__device__ __forceinline__ void swap32(unsigned &a, unsigned &b) {
  asm volatile("v_permlane32_swap_b32 %0, %1" : "+v"(a), "+v"(b));
}
__device__ __forceinline__ float fexp2(float x) {
  float r; asm("v_exp_f32 %0, %1" : "=v"(r) : "v"(x)); return r;
}

typedef const __attribute__((address_space(1))) void gv_t;
typedef __attribute__((address_space(3))) void lv_t;
__device__ __forceinline__ void gload16(const void* g, void* l) {
  __builtin_amdgcn_global_load_lds((gv_t*)g, (lv_t*)l, 16, 0, 0);
}

// ---------------------------------------------------------------- fp32 -> bf16
__global__ void f2b(const float* __restrict__ s, bf16* __restrict__ d, int n)
{
  int i = blockIdx.x*blockDim.x + threadIdx.x;
  int stride = gridDim.x*blockDim.x;
  for (int idx = i*4; idx < n; idx += stride*4) {
    float4 v = *(const float4*)(s + idx);
    __hip_bfloat16 b0 = __float2bfloat16(v.x);
    __hip_bfloat16 b1 = __float2bfloat16(v.y);
    __hip_bfloat16 b2 = __float2bfloat16(v.z);
    __hip_bfloat16 b3 = __float2bfloat16(v.w);
    ushort4 o;
    o.x = *reinterpret_cast<unsigned short*>(&b0);
    o.y = *reinterpret_cast<unsigned short*>(&b1);
    o.z = *reinterpret_cast<unsigned short*>(&b2);
    o.w = *reinterpret_cast<unsigned short*>(&b3);
    *(ushort4*)((unsigned short*)d + idx) = o;
  }
}

// ------------------------------------------------- C[M,N] = A[M,K] @ Bt[N,K]^T
template<typename OutT>
__global__ __launch_bounds__(256) void gemm_bt(
    const bf16* __restrict__ A, const bf16* __restrict__ Bt, OutT* __restrict__ C,
    int M, int N, int K)
{
  __shared__ bf16 As[128*64];
  __shared__ bf16 Bs[128*64];
  const int tid = threadIdx.x;
  const int w = tid >> 6, l = tid & 63;
  const int l15 = l & 15, lhi = l >> 4;
  const int m0 = blockIdx.y * 128, n0 = blockIdx.x * 128;
  const int wr = w >> 1, wc = w & 1;

  f32x4 acc[4][4];
  #pragma unroll
  for (int m = 0; m < 4; ++m)
    #pragma unroll
    for (int n = 0; n < 4; ++n)
      #pragma unroll
      for (int e = 0; e < 4; ++e) acc[m][n][e] = 0.f;

  const int srow = l >> 3;
  const int scol = (l & 7)*8;

  for (int k0 = 0; k0 < K; k0 += 64) {
    __syncthreads();
    #pragma unroll
    for (int i = 0; i < 4; ++i) {
      const int ci = w*4 + i;
      const int r = ci*8 + srow;
      gload16(A  + (size_t)(m0 + r)*K + k0 + scol, &As[r*64 + scol]);
      gload16(Bt + (size_t)(n0 + r)*K + k0 + scol, &Bs[r*64 + scol]);
    }
    __syncthreads();
    #pragma unroll
    for (int kk = 0; kk < 2; ++kk) {
      bf16x8 af[4], bfr[4];
      #pragma unroll
      for (int m = 0; m < 4; ++m)
        af[m] = *(const bf16x8*)&As[(wr*64 + m*16 + l15)*64 + kk*32 + lhi*8];
      #pragma unroll
      for (int n = 0; n < 4; ++n)
        bfr[n] = *(const bf16x8*)&Bs[(wc*64 + n*16 + l15)*64 + kk*32 + lhi*8];
      #pragma unroll
      for (int m = 0; m < 4; ++m)
        #pragma unroll
        for (int n = 0; n < 4; ++n)
          acc[m][n] = mfma16(af[m], bfr[n], acc[m][n]);
    }
  }

  #pragma unroll
  for (int m = 0; m < 4; ++m) {
    const int crow = m0 + wr*64 + m*16 + lhi*4;
    #pragma unroll
    for (int n = 0; n < 4; ++n) {
      const int ccol = n0 + wc*64 + n*16 + l15;
      #pragma unroll
      for (int j = 0; j < 4; ++j) {
        if constexpr (sizeof(OutT) == 2)
          C[(size_t)(crow + j)*N + ccol] = __float2bfloat16(acc[m][n][j]);
        else
          C[(size_t)(crow + j)*N + ccol] = acc[m][n][j];
      }
    }
  }
}

// ------------------------------------- RMSNorm(head of 128) + RoPE, relayout
// q path additionally folds 1/sqrt(128) * log2(e) (exp2-domain softmax).
__global__ __launch_bounds__(256) void normrope(
    const bf16* __restrict__ src, bf16* __restrict__ dst,
    const float* __restrict__ cosb, const float* __restrict__ sinb,
    const float* __restrict__ w, int nh, float scale)
{
  const int wid = threadIdx.x >> 6, lane = threadIdx.x & 63;
  const int row = blockIdx.x*4 + wid;
  const int m = row / nh, h = row % nh;
  const int b = m / SS, s = m % SS;
  const bf16* sp = src + (size_t)m*nh*HD + h*HD;
  float v1 = __bfloat162float(sp[lane]);
  float v2 = __bfloat162float(sp[lane + 64]);
  float ss = v1*v1 + v2*v2;
  #pragma unroll
  for (int msk = 1; msk < 64; msk <<= 1) ss += __shfl_xor(ss, msk);
  float r = rsqrtf(ss*(1.f/128.f) + 1e-6f) * scale;
  float n1 = v1*r*w[lane], n2 = v2*r*w[lane + 64];
  const float* cp  = cosb + (size_t)m*HD;
  const float* sip = sinb + (size_t)m*HD;
  float o1 = n1*cp[lane]      - n2*sip[lane];
  float o2 = n2*cp[lane + 64] + n1*sip[lane + 64];
  bf16* dp = dst + ((size_t)(b*nh + h)*SS + s)*HD;
  dp[lane]      = __float2bfloat16(o1);
  dp[lane + 64] = __float2bfloat16(o2);
}

// --------------------------- v0[b,s,(kv,d)] -> vt[b,kv,d,s]  (LDS transpose)
__global__ __launch_bounds__(256) void vtrans(const bf16* __restrict__ v0,
                                              bf16* __restrict__ vt)
{
  __shared__ bf16 tile[64][65];
  const int s0 = blockIdx.x*64, d0 = blockIdx.y*64, bkv = blockIdx.z;
  const int bb = bkv >> 3, kv = bkv & 7;
  const int c = threadIdx.x & 63, rbase = threadIdx.x >> 6;
  #pragma unroll
  for (int r = 0; r < 64; r += 4) {
    int sl = r + rbase;
    tile[sl][c] = v0[(size_t)(bb*SS + s0 + sl)*(NKV*HD) + kv*HD + d0 + c];
  }
  __syncthreads();
  #pragma unroll
  for (int r = 0; r < 64; r += 4) {
    int dl = r + rbase;
    vt[((size_t)bkv*HD + d0 + dl)*SS + s0 + c] = tile[c][dl];
  }
}

// ------------------------------------------------ causal GQA flash attention
// m214-style: 8 waves x 32 q-rows, KVBLK=64, swapped QK^T (mfma(K,Q)) with
// 32x32x16 so softmax is lane-local; cvt_pk+permlane32_swap P re-fragment;
// swapped PV (mfma(V,P)) keeps q lane-local for scalar rescale; defer-max;
// XOR-swizzled K/V LDS; balanced causal pairing (j, 15-j); XCD-chunked grid.
__global__ __launch_bounds__(512, 2) void attn_fwd(
    const bf16* __restrict__ qr, const bf16* __restrict__ kr,
    const bf16* __restrict__ vt, bf16* __restrict__ ao)
{
  __shared__ __align__(16) char smem[32768];
  char* KsB = smem;             // [64 kv][256B], byte ^= (row&7)<<4 per 16B slot
  char* VsB = smem + 16384;     // [128 d][128B], same swizzle

  const int L = blockIdx.x;
  const int orig = (L & 7)*64 + (L >> 3);      // XCD-chunk: 64 consecutive per XCD
  const int bh = orig >> 3, j = orig & 7;      // 8 q-block pairs per (b,h)
  const int b = bh >> 5, h = bh & 31, kvh = h >> 2;

  const int tid = threadIdx.x;
  const int wid = tid >> 6, lane = tid & 63;
  const int l31 = lane & 31, hi = lane >> 5;
  const unsigned hi16 = hi << 4;
  const unsigned swz = (lane & 7) << 4;

  // waves 0-3: q-block j (rows j*128..), waves 4-7: q-block 15-j
  const int qw0 = (wid < 4) ? (j*128 + wid*32) : ((15 - j)*128 + (wid - 4)*32);
  const int NT = 32 - 2*j;                     // tiles needed by the high block
  const int qlane = qw0 + l31;

  const bf16* Qp = qr + ((size_t)(b*NH + h)*SS + qlane)*HD;
  const bf16* Kp = kr + (size_t)(b*NKV + kvh)*SS*HD;
  const bf16* Vp = vt + (size_t)(b*NKV + kvh)*HD*SS;    // [HD][S]

  // staging: 512 threads x (2 K + 2 V) 16B chunks = 32KB/tile
  const int krow = tid >> 3;            // 0..63
  const int kslot = (tid & 7)*2;        // two adjacent 16B slots of the 256B row
  const int vrow = tid >> 2;            // 0..127
  const int vslot = (tid & 3)*2;        // two adjacent 16B slots of the 128B row
  const bf16* kg = Kp + (size_t)krow*HD + kslot*8;
  const bf16* vg = Vp + (size_t)vrow*SS + vslot*8;
  char* kl0 = KsB + krow*256 + (((unsigned)(kslot*16))     ^ ((krow & 7) << 4));
  char* kl1 = KsB + krow*256 + (((unsigned)((kslot+1)*16)) ^ ((krow & 7) << 4));
  char* vl0 = VsB + vrow*128 + (((unsigned)(vslot*16))     ^ ((vrow & 7) << 4));
  char* vl1 = VsB + vrow*128 + (((unsigned)((vslot+1)*16)) ^ ((vrow & 7) << 4));

  float4 kp0 = *(const float4*)(kg);
  float4 kp1 = *(const float4*)(kg + 8);
  float4 vp0 = *(const float4*)(vg);
  float4 vp1 = *(const float4*)(vg + 8);
  *(float4*)kl0 = kp0; *(float4*)kl1 = kp1;
  *(float4*)vl0 = vp0; *(float4*)vl1 = vp1;
  __syncthreads();

  bf16x8 qf[8];
  #pragma unroll
  for (int kd = 0; kd < 8; ++kd)
    qf[kd] = *(const bf16x8*)(Qp + kd*16 + hi*8);

  f32x16 o0, o1, o2, o3;
  #pragma unroll
  for (int r = 0; r < 16; ++r) { o0[r] = 0.f; o1[r] = 0.f; o2[r] = 0.f; o3[r] = 0.f; }
  float mrow = -1e30f, lrow = 0.f;

  for (int t = 0; t < NT; ++t) {
    const int kv0 = t*64;
    const bool haveNext = (t + 1 < NT);
    if (haveNext) {                      // T14: issue next-tile loads early
      const bf16* kgn = kg + (size_t)(kv0 + 64)*HD;
      const bf16* vgn = vg + kv0 + 64;
      kp0 = *(const float4*)(kgn);
      kp1 = *(const float4*)(kgn + 8);
      vp0 = *(const float4*)(vgn);
      vp1 = *(const float4*)(vgn + 8);
    }

    if (kv0 <= qw0 + 31) {               // wave-uniform causal activity
      // ---- QK^T swapped: S^T[kv][q], lane q = l31, kv rows in regs
      f32x16 s0, s1;
      #pragma unroll
      for (int r = 0; r < 16; ++r) { s0[r] = 0.f; s1[r] = 0.f; }
      #pragma unroll
      for (int kd = 0; kd < 8; ++kd) {
        bf16x8 k0f = *(const bf16x8*)(KsB + l31*256        + (((unsigned)(kd*32) + hi16) ^ swz));
        bf16x8 k1f = *(const bf16x8*)(KsB + (32 + l31)*256 + (((unsigned)(kd*32) + hi16) ^ swz));
        s0 = mfma32(k0f, qf[kd], s0);
        s1 = mfma32(k1f, qf[kd], s1);
      }
      if (kv0 + 63 > qw0) {              // diagonal-region masking
        #pragma unroll
        for (int r = 0; r < 16; ++r) {
          const int off = (r & 3) + 8*(r >> 2) + 4*hi;
          if (kv0 + off > qlane)      s0[r] = -1e30f;
          if (kv0 + 32 + off > qlane) s1[r] = -1e30f;
        }
      }
      // ---- online softmax, lane-local (q = l31); other half via lane^32
      float tmax = s0[0];
      #pragma unroll
      for (int r = 1; r < 16; ++r) tmax = fmaxf(tmax, s0[r]);
      #pragma unroll
      for (int r = 0; r < 16; ++r) tmax = fmaxf(tmax, s1[r]);
      tmax = fmaxf(tmax, __shfl_xor(tmax, 32));
      if (!__all(tmax <= mrow + 8.f)) {  // T13 defer-max (log2 domain)
        float mnew = fmaxf(mrow, tmax);
        float alpha = fexp2(mrow - mnew);
        mrow = mnew;
        lrow *= alpha;
        #pragma unroll
        for (int r = 0; r < 16; ++r) {
          o0[r] *= alpha; o1[r] *= alpha; o2[r] *= alpha; o3[r] *= alpha;
        }
      }
      float tsum = 0.f;
      #pragma unroll
      for (int r = 0; r < 16; ++r) { s0[r] = fexp2(s0[r] - mrow); tsum += s0[r]; }
      #pragma unroll
      for (int r = 0; r < 16; ++r) { s1[r] = fexp2(s1[r] - mrow); tsum += s1[r]; }
      tsum += __shfl_xor(tsum, 32);
      lrow += tsum;

      // ---- PV swapped: O^T-free form mfma(V, P) -> D[d][q], q = l31
      #pragma unroll
      for (int ks = 0; ks < 4; ++ks) {
        const int bb0 = (ks & 1)*8;
        float p0,p1,p2,p3,p4,p5,p6,p7;
        if (ks < 2) { p0=s0[bb0+0];p1=s0[bb0+1];p2=s0[bb0+2];p3=s0[bb0+3];
                      p4=s0[bb0+4];p5=s0[bb0+5];p6=s0[bb0+6];p7=s0[bb0+7]; }
        else        { p0=s1[bb0+0];p1=s1[bb0+1];p2=s1[bb0+2];p3=s1[bb0+3];
                      p4=s1[bb0+4];p5=s1[bb0+5];p6=s1[bb0+6];p7=s1[bb0+7]; }
        unsigned c01 = cvtpk(p0,p1), c23 = cvtpk(p2,p3);
        unsigned c45 = cvtpk(p4,p5), c67 = cvtpk(p6,p7);
        unsigned w0 = c01, w2 = c45; swap32(w0, w2);
        unsigned w1 = c23, w3 = c67; swap32(w1, w3);
        union { unsigned u[4]; bf16x8 v; } pa;
        pa.u[0]=w0; pa.u[1]=w1; pa.u[2]=w2; pa.u[3]=w3;
        #pragma unroll
        for (int dt = 0; dt < 4; ++dt) {
          bf16x8 vf = *(const bf16x8*)(VsB + (dt*32 + l31)*128 +
                                       (((unsigned)(ks*32) + hi16) ^ swz));
          f32x16 &oo = (dt==0)?o0:(dt==1)?o1:(dt==2)?o2:o3;
          oo = mfma32(vf, pa.v, oo);
        }
      }
    }

    __syncthreads();                     // all waves done reading Ks/Vs
    if (haveNext) {
      *(float4*)kl0 = kp0; *(float4*)kl1 = kp1;
      *(float4*)vl0 = vp0; *(float4*)vl1 = vp1;
    }
    __syncthreads();
  }

  // ---- epilogue: transpose O via wave-private LDS, coalesced 16B stores
  const float invl = 1.f / lrow;
  char* ow = smem + wid*4096;            // [32 q][128B] per wave, swizzled
  bf16* aop = ao + ((size_t)b*SS + qlane)*HH + h*HD;
  const unsigned eswz = (l31 & 7) << 4;
  #pragma unroll
  for (int half = 0; half < 2; ++half) {
    #pragma unroll
    for (int hh = 0; hh < 2; ++hh) {
      #pragma unroll
      for (int r = 0; r < 16; ++r) {
        const int dcol = hh*32 + (r & 3) + 8*(r >> 2) + 4*hi;   // 0..63
        float val = ((half*2+hh)==0 ? o0[r] : (half*2+hh)==1 ? o1[r]
                     : (half*2+hh)==2 ? o2[r] : o3[r]) * invl;
        *(bf16*)(ow + l31*128 + (((unsigned)(dcol*2)) ^ eswz)) = __float2bfloat16(val);
      }
    }
    #pragma unroll
    for (int m = 0; m < 4; ++m) {
      const int c0 = hi*32 + m*8;
      bf16x8 vv = *(const bf16x8*)(ow + l31*128 + (((unsigned)(c0*2)) ^ eswz));
      *(bf16x8*)(aop + half*64 + c0) = vv;
    }
  }
}

// --------------------------------------------------------------------- launch
extern "C" void kernel_launch(void* const* d_in, const int* in_sizes, int n_in,
                              void* d_out, int out_size, void* d_ws, size_t ws_size,
                              hipStream_t stream)
{
  const float* x    = (const float*)d_in[0];
  const float* cosb = (const float*)d_in[1];
  const float* sinb = (const float*)d_in[2];
  const float* wq   = (const float*)d_in[3];
  const float* wk   = (const float*)d_in[4];
  const float* wv   = (const float*)d_in[5];
  const float* wo   = (const float*)d_in[6];
  const float* qnw  = (const float*)d_in[7];
  const float* knw  = (const float*)d_in[8];
  float* out = (float*)d_out;

  char* ws = (char*)d_ws;
  bf16* xb  = (bf16*)(ws);                  // 32 MiB
  bf16* wqb = (bf16*)(ws +  33554432);      // 32 MiB
  bf16* wkb = (bf16*)(ws +  67108864);      //  8 MiB
  bf16* wvb = (bf16*)(ws +  75497472);      //  8 MiB
  bf16* wob = (bf16*)(ws +  83886080);      // 32 MiB
  bf16* q0  = (bf16*)(ws + 117440512);      // 32 MiB
  bf16* k0  = (bf16*)(ws + 150994944);      //  8 MiB
  bf16* v0  = (bf16*)(ws + 159383552);      //  8 MiB
  bf16* qr  = (bf16*)(ws + 167772160);      // 32 MiB  (end 192 MiB)
  bf16* vt = xb;    // xb dead after QKV GEMMs
  bf16* kr = wqb;   // wqb dead after Q GEMM
  bf16* ao = q0;    // q0 dead after q normrope

  f2b<<<2048, 256, 0, stream>>>(x,  xb,  MR*HH);
  f2b<<<2048, 256, 0, stream>>>(wq, wqb, NH*HD*HH);
  f2b<<<2048, 256, 0, stream>>>(wk, wkb, NKV*HD*HH);
  f2b<<<2048, 256, 0, stream>>>(wv, wvb, NKV*HD*HH);
  f2b<<<2048, 256, 0, stream>>>(wo, wob, HH*NH*HD);

  gemm_bt<bf16><<<dim3(32, 32), 256, 0, stream>>>(xb, wqb, q0, MR, 4096, HH);
  gemm_bt<bf16><<<dim3( 8, 32), 256, 0, stream>>>(xb, wkb, k0, MR, 1024, HH);
  gemm_bt<bf16><<<dim3( 8, 32), 256, 0, stream>>>(xb, wvb, v0, MR, 1024, HH);

  // q scale folds 1/sqrt(HD) * log2(e) for exp2-domain softmax
  normrope<<<(MR*NH)/4,  256, 0, stream>>>(q0, qr, cosb, sinb, qnw, NH,
                                           0.08838834764831845f*1.44269504088896341f);
  normrope<<<(MR*NKV)/4, 256, 0, stream>>>(k0, kr, cosb, sinb, knw, NKV, 1.0f);
  vtrans<<<dim3(32, 2, 16), 256, 0, stream>>>(v0, vt);

  attn_fwd<<<512, 512, 0, stream>>>(qr, kr, vt, ao);

  gemm_bt<float><<<dim3(32, 32), 256, 0, stream>>>(ao, wob, out, MR, HH, HH);
}

// Round 4
// 588.172 us; speedup vs baseline: 4.5130x; 1.3093x over previous
//
#include <hip/hip_runtime.h>
#include <hip/hip_bf16.h>

#define NB  2
#define SS  2048
#define HH  4096
#define NH  32
#define NKV 8
#define HD  128
#define MR  (NB*SS)   // 4096 token rows

typedef __bf16 bf16x8 __attribute__((ext_vector_type(8)));
typedef float  f32x4  __attribute__((ext_vector_type(4)));
typedef float  f32x16 __attribute__((ext_vector_type(16)));
using bf16 = __hip_bfloat16;

__device__ __forceinline__ f32x4 mfma16(bf16x8 a, bf16x8 b, f32x4 c) {
  return __builtin_amdgcn_mfma_f32_16x16x32_bf16(a, b, c, 0, 0, 0);
}
__device__ __forceinline__ f32x16 mfma32(bf16x8 a, bf16x8 b, f32x16 c) {
  return __builtin_amdgcn_mfma_f32_32x32x16_bf16(a, b, c, 0, 0, 0);
}
__device__ __forceinline__ unsigned cvtpk(float lo, float hi) {
  unsigned r; asm("v_cvt_pk_bf16_f32 %0, %1, %2" : "=v"(r) : "v"(lo), "v"(hi));
  return r;
}
__device__ __forceinline__ void swap32(unsigned &a, unsigned &b) {
  asm volatile("v_permlane32_swap_b32 %0, %1" : "+v"(a), "+v"(b));
}
__device__ __forceinline__ float fexp2(float x) {
  float r; asm("v_exp_f32 %0, %1" : "=v"(r) : "v"(x)); return r;
}

typedef const __attribute__((address_space(1))) void gv_t;
typedef __attribute__((address_space(3))) void lv_t;
__device__ __forceinline__ void gload16(const void* g, void* l) {
  __builtin_amdgcn_global_load_lds((gv_t*)g, (lv_t*)l, 16, 0, 0);
}

// ---------------------------------------------------------------- fp32 -> bf16
__global__ void f2b(const float* __restrict__ s, bf16* __restrict__ d, int n)
{
  int i = blockIdx.x*blockDim.x + threadIdx.x;
  int stride = gridDim.x*blockDim.x;
  for (int idx = i*4; idx < n; idx += stride*4) {
    float4 v = *(const float4*)(s + idx);
    __hip_bfloat16 b0 = __float2bfloat16(v.x);
    __hip_bfloat16 b1 = __float2bfloat16(v.y);
    __hip_bfloat16 b2 = __float2bfloat16(v.z);
    __hip_bfloat16 b3 = __float2bfloat16(v.w);
    ushort4 o;
    o.x = *reinterpret_cast<unsigned short*>(&b0);
    o.y = *reinterpret_cast<unsigned short*>(&b1);
    o.z = *reinterpret_cast<unsigned short*>(&b2);
    o.w = *reinterpret_cast<unsigned short*>(&b3);
    *(ushort4*)((unsigned short*)d + idx) = o;
  }
}

// ------------------------------------------------- C[M,N] = A[M,K] @ Bt[N,K]^T
// 256x256 tile, BK=64 (2 ksubs of 32), 8 waves (2M x 4N), double-buffered LDS
// [2][A/B][2 ksub][256x32], counted vmcnt(4) + raw barriers (T3/T4), XOR slot
// swizzle with pre-swizzled global source for global_load_lds (T2, rule 21),
// setprio around MFMA cluster (T5), XCD-chunked grid (T1).
template<typename OutT>
__global__ __launch_bounds__(512, 2) void gemm256(
    const bf16* __restrict__ A, const bf16* __restrict__ Bt, OutT* __restrict__ C,
    int M, int N, int K, int tilesX)
{
  __shared__ bf16 lds[2][2][2][256*32];   // 128 KiB

  const int bid = blockIdx.x;
  const int cpx = gridDim.x >> 3;          // grid divisible by 8
  const int wg  = (bid & 7)*cpx + (bid >> 3);
  const int m0 = (wg / tilesX) * 256, n0 = (wg % tilesX) * 256;

  const int tid = threadIdx.x;
  const int l = tid & 63;
  const int l15 = l & 15, lhi = l >> 4;
  const int wid = tid >> 6;
  const int wr = wid >> 2, wc = wid & 3;   // 2 x 4 wave grid, 128x64 out/wave

  // ---- staging geometry: thread covers granules tid, tid+512 of each 16KB
  // region; LDS dest is linear (wave base + lane*16), global source slot is
  // pre-swizzled so readers can XOR-decode (involution at 16B granularity).
  const int srow  = tid >> 2;              // 0..127 (+128 for 2nd granule)
  const int sslot = tid & 3;
  const int sxs   = sslot ^ (srow & 3);    // (srow+128)&3 == srow&3
  const bf16* ga0 = A  + (size_t)(m0 + srow)*K       + sxs*8;
  const bf16* ga1 = A  + (size_t)(m0 + srow + 128)*K + sxs*8;
  const bf16* gb0 = Bt + (size_t)(n0 + srow)*K       + sxs*8;
  const bf16* gb1 = Bt + (size_t)(n0 + srow + 128)*K + sxs*8;
  const int ldst = srow*32 + sslot*8;      // element offset within region

#define STAGE(buf, s, kadd) do {                                  \
    gload16(ga0 + (kadd), &lds[buf][0][s][ldst]);                 \
    gload16(ga1 + (kadd), &lds[buf][0][s][ldst + 128*32]);        \
    gload16(gb0 + (kadd), &lds[buf][1][s][ldst]);                 \
    gload16(gb1 + (kadd), &lds[buf][1][s][ldst + 128*32]);        \
  } while (0)

  f32x4 acc[8][4];
  #pragma unroll
  for (int fm = 0; fm < 8; ++fm)
    #pragma unroll
    for (int fn = 0; fn < 4; ++fn)
      #pragma unroll
      for (int e = 0; e < 4; ++e) acc[fm][fn][e] = 0.f;

  // fragment read addressing (XOR-decoded slot; uniform over 8 bank groups)
  const int slotoff = (lhi ^ (l15 & 3))*8;
  const int arow = wr*128 + l15;
  const int brow = wc*64  + l15;

  const int nt = K >> 6;
  // prologue: stage tile 0 (both ksubs) into buf 0
  STAGE(0, 0, 0);
  STAGE(0, 1, 32);
  asm volatile("s_waitcnt vmcnt(4)" ::: "memory");
  __builtin_amdgcn_s_barrier();

  for (int t = 0; t < nt; ++t) {
    const int p = t & 1;
    const bool pf = (t + 1 < nt);
    const int kn = (t + 1) << 6;
    #pragma unroll
    for (int s = 0; s < 2; ++s) {
      if (pf) {                            // stage tile t+1 ksub s -> buf p^1
        if (s == 0) STAGE(p ^ 1, 0, kn);
        else        STAGE(p ^ 1, 1, kn + 32);
      }
      bf16x8 af[8], bfr[4];
      #pragma unroll
      for (int fm = 0; fm < 8; ++fm)
        af[fm] = *(const bf16x8*)&lds[p][0][s][(arow + fm*16)*32 + slotoff];
      #pragma unroll
      for (int fn = 0; fn < 4; ++fn)
        bfr[fn] = *(const bf16x8*)&lds[p][1][s][(brow + fn*16)*32 + slotoff];
      __builtin_amdgcn_s_setprio(1);
      #pragma unroll
      for (int fm = 0; fm < 8; ++fm)
        #pragma unroll
        for (int fn = 0; fn < 4; ++fn)
          acc[fm][fn] = mfma16(af[fm], bfr[fn], acc[fm][fn]);
      __builtin_amdgcn_s_setprio(0);
      if (pf) asm volatile("s_waitcnt vmcnt(4)" ::: "memory");
      else    asm volatile("s_waitcnt vmcnt(0)" ::: "memory");
      __builtin_amdgcn_s_barrier();
    }
  }
#undef STAGE

  #pragma unroll
  for (int fm = 0; fm < 8; ++fm) {
    const int crow = m0 + wr*128 + fm*16 + lhi*4;
    #pragma unroll
    for (int fn = 0; fn < 4; ++fn) {
      const int ccol = n0 + wc*64 + fn*16 + l15;
      #pragma unroll
      for (int j = 0; j < 4; ++j) {
        if constexpr (sizeof(OutT) == 2)
          C[(size_t)(crow + j)*N + ccol] = __float2bfloat16(acc[fm][fn][j]);
        else
          C[(size_t)(crow + j)*N + ccol] = acc[fm][fn][j];
      }
    }
  }
}

// ------------------------------------- RMSNorm(head of 128) + RoPE, relayout
__global__ __launch_bounds__(256) void normrope(
    const bf16* __restrict__ src, bf16* __restrict__ dst,
    const float* __restrict__ cosb, const float* __restrict__ sinb,
    const float* __restrict__ w, int nh, float scale, int rowstride, int coloff)
{
  const int wid = threadIdx.x >> 6, lane = threadIdx.x & 63;
  const int row = blockIdx.x*4 + wid;
  const int m = row / nh, h = row % nh;
  const int b = m / SS, s = m % SS;
  const bf16* sp = src + (size_t)m*rowstride + coloff + h*HD;
  float v1 = __bfloat162float(sp[lane]);
  float v2 = __bfloat162float(sp[lane + 64]);
  float ss = v1*v1 + v2*v2;
  #pragma unroll
  for (int msk = 1; msk < 64; msk <<= 1) ss += __shfl_xor(ss, msk);
  float r = rsqrtf(ss*(1.f/128.f) + 1e-6f) * scale;
  float n1 = v1*r*w[lane], n2 = v2*r*w[lane + 64];
  const float* cp  = cosb + (size_t)m*HD;
  const float* sip = sinb + (size_t)m*HD;
  float o1 = n1*cp[lane]      - n2*sip[lane];
  float o2 = n2*cp[lane + 64] + n1*sip[lane + 64];
  bf16* dp = dst + ((size_t)(b*nh + h)*SS + s)*HD;
  dp[lane]      = __float2bfloat16(o1);
  dp[lane + 64] = __float2bfloat16(o2);
}

// --------------------------- src[m, coloff+kv*HD+d] -> vt[b,kv,d,s]
__global__ __launch_bounds__(256) void vtrans(const bf16* __restrict__ v0,
                                              bf16* __restrict__ vt,
                                              int rowstride, int coloff)
{
  __shared__ bf16 tile[64][65];
  const int s0 = blockIdx.x*64, d0 = blockIdx.y*64, bkv = blockIdx.z;
  const int bb = bkv >> 3, kv = bkv & 7;
  const int c = threadIdx.x & 63, rbase = threadIdx.x >> 6;
  #pragma unroll
  for (int r = 0; r < 64; r += 4) {
    int sl = r + rbase;
    tile[sl][c] = v0[(size_t)(bb*SS + s0 + sl)*rowstride + coloff + kv*HD + d0 + c];
  }
  __syncthreads();
  #pragma unroll
  for (int r = 0; r < 64; r += 4) {
    int dl = r + rbase;
    vt[((size_t)bkv*HD + d0 + dl)*SS + s0 + c] = tile[c][dl];
  }
}

// ------------------------------------------------ causal GQA flash attention
__global__ __launch_bounds__(512, 2) void attn_fwd(
    const bf16* __restrict__ qr, const bf16* __restrict__ kr,
    const bf16* __restrict__ vt, bf16* __restrict__ ao)
{
  __shared__ __align__(16) char smem[32768];
  char* KsB = smem;             // [64 kv][256B], byte ^= (row&7)<<4 per 16B slot
  char* VsB = smem + 16384;     // [128 d][128B], same swizzle

  const int L = blockIdx.x;
  const int orig = (L & 7)*64 + (L >> 3);
  const int bh = orig >> 3, j = orig & 7;
  const int b = bh >> 5, h = bh & 31, kvh = h >> 2;

  const int tid = threadIdx.x;
  const int wid = tid >> 6, lane = tid & 63;
  const int l31 = lane & 31, hi = lane >> 5;
  const unsigned hi16 = hi << 4;
  const unsigned swz = (lane & 7) << 4;

  const int qw0 = (wid < 4) ? (j*128 + wid*32) : ((15 - j)*128 + (wid - 4)*32);
  const int NT = 32 - 2*j;
  const int qlane = qw0 + l31;

  const bf16* Qp = qr + ((size_t)(b*NH + h)*SS + qlane)*HD;
  const bf16* Kp = kr + (size_t)(b*NKV + kvh)*SS*HD;
  const bf16* Vp = vt + (size_t)(b*NKV + kvh)*HD*SS;

  const int krow = tid >> 3;
  const int kslot = (tid & 7)*2;
  const int vrow = tid >> 2;
  const int vslot = (tid & 3)*2;
  const bf16* kg = Kp + (size_t)krow*HD + kslot*8;
  const bf16* vg = Vp + (size_t)vrow*SS + vslot*8;
  char* kl0 = KsB + krow*256 + (((unsigned)(kslot*16))     ^ ((krow & 7) << 4));
  char* kl1 = KsB + krow*256 + (((unsigned)((kslot+1)*16)) ^ ((krow & 7) << 4));
  char* vl0 = VsB + vrow*128 + (((unsigned)(vslot*16))     ^ ((vrow & 7) << 4));
  char* vl1 = VsB + vrow*128 + (((unsigned)((vslot+1)*16)) ^ ((vrow & 7) << 4));

  float4 kp0 = *(const float4*)(kg);
  float4 kp1 = *(const float4*)(kg + 8);
  float4 vp0 = *(const float4*)(vg);
  float4 vp1 = *(const float4*)(vg + 8);
  *(float4*)kl0 = kp0; *(float4*)kl1 = kp1;
  *(float4*)vl0 = vp0; *(float4*)vl1 = vp1;
  __syncthreads();

  bf16x8 qf[8];
  #pragma unroll
  for (int kd = 0; kd < 8; ++kd)
    qf[kd] = *(const bf16x8*)(Qp + kd*16 + hi*8);

  f32x16 o0, o1, o2, o3;
  #pragma unroll
  for (int r = 0; r < 16; ++r) { o0[r] = 0.f; o1[r] = 0.f; o2[r] = 0.f; o3[r] = 0.f; }
  float mrow = -1e30f, lrow = 0.f;

  for (int t = 0; t < NT; ++t) {
    const int kv0 = t*64;
    const bool haveNext = (t + 1 < NT);
    if (haveNext) {
      const bf16* kgn = kg + (size_t)(kv0 + 64)*HD;
      const bf16* vgn = vg + kv0 + 64;
      kp0 = *(const float4*)(kgn);
      kp1 = *(const float4*)(kgn + 8);
      vp0 = *(const float4*)(vgn);
      vp1 = *(const float4*)(vgn + 8);
    }

    if (kv0 <= qw0 + 31) {
      f32x16 s0, s1;
      #pragma unroll
      for (int r = 0; r < 16; ++r) { s0[r] = 0.f; s1[r] = 0.f; }
      #pragma unroll
      for (int kd = 0; kd < 8; ++kd) {
        bf16x8 k0f = *(const bf16x8*)(KsB + l31*256        + (((unsigned)(kd*32) + hi16) ^ swz));
        bf16x8 k1f = *(const bf16x8*)(KsB + (32 + l31)*256 + (((unsigned)(kd*32) + hi16) ^ swz));
        s0 = mfma32(k0f, qf[kd], s0);
        s1 = mfma32(k1f, qf[kd], s1);
      }
      if (kv0 + 63 > qw0) {
        #pragma unroll
        for (int r = 0; r < 16; ++r) {
          const int off = (r & 3) + 8*(r >> 2) + 4*hi;
          if (kv0 + off > qlane)      s0[r] = -1e30f;
          if (kv0 + 32 + off > qlane) s1[r] = -1e30f;
        }
      }
      float tmax = s0[0];
      #pragma unroll
      for (int r = 1; r < 16; ++r) tmax = fmaxf(tmax, s0[r]);
      #pragma unroll
      for (int r = 0; r < 16; ++r) tmax = fmaxf(tmax, s1[r]);
      tmax = fmaxf(tmax, __shfl_xor(tmax, 32));
      if (!__all(tmax <= mrow + 8.f)) {
        float mnew = fmaxf(mrow, tmax);
        float alpha = fexp2(mrow - mnew);
        mrow = mnew;
        lrow *= alpha;
        #pragma unroll
        for (int r = 0; r < 16; ++r) {
          o0[r] *= alpha; o1[r] *= alpha; o2[r] *= alpha; o3[r] *= alpha;
        }
      }
      float tsum = 0.f;
      #pragma unroll
      for (int r = 0; r < 16; ++r) { s0[r] = fexp2(s0[r] - mrow); tsum += s0[r]; }
      #pragma unroll
      for (int r = 0; r < 16; ++r) { s1[r] = fexp2(s1[r] - mrow); tsum += s1[r]; }
      tsum += __shfl_xor(tsum, 32);
      lrow += tsum;

      #pragma unroll
      for (int ks = 0; ks < 4; ++ks) {
        const int bb0 = (ks & 1)*8;
        float p0,p1,p2,p3,p4,p5,p6,p7;
        if (ks < 2) { p0=s0[bb0+0];p1=s0[bb0+1];p2=s0[bb0+2];p3=s0[bb0+3];
                      p4=s0[bb0+4];p5=s0[bb0+5];p6=s0[bb0+6];p7=s0[bb0+7]; }
        else        { p0=s1[bb0+0];p1=s1[bb0+1];p2=s1[bb0+2];p3=s1[bb0+3];
                      p4=s1[bb0+4];p5=s1[bb0+5];p6=s1[bb0+6];p7=s1[bb0+7]; }
        unsigned c01 = cvtpk(p0,p1), c23 = cvtpk(p2,p3);
        unsigned c45 = cvtpk(p4,p5), c67 = cvtpk(p6,p7);
        unsigned w0 = c01, w2 = c45; swap32(w0, w2);
        unsigned w1 = c23, w3 = c67; swap32(w1, w3);
        union { unsigned u[4]; bf16x8 v; } pa;
        pa.u[0]=w0; pa.u[1]=w1; pa.u[2]=w2; pa.u[3]=w3;
        #pragma unroll
        for (int dt = 0; dt < 4; ++dt) {
          bf16x8 vf = *(const bf16x8*)(VsB + (dt*32 + l31)*128 +
                                       (((unsigned)(ks*32) + hi16) ^ swz));
          f32x16 &oo = (dt==0)?o0:(dt==1)?o1:(dt==2)?o2:o3;
          oo = mfma32(vf, pa.v, oo);
        }
      }
    }

    __syncthreads();
    if (haveNext) {
      *(float4*)kl0 = kp0; *(float4*)kl1 = kp1;
      *(float4*)vl0 = vp0; *(float4*)vl1 = vp1;
    }
    __syncthreads();
  }

  const float invl = 1.f / lrow;
  char* ow = smem + wid*4096;
  bf16* aop = ao + ((size_t)b*SS + qlane)*HH + h*HD;
  const unsigned eswz = (l31 & 7) << 4;
  #pragma unroll
  for (int half = 0; half < 2; ++half) {
    #pragma unroll
    for (int hh = 0; hh < 2; ++hh) {
      #pragma unroll
      for (int r = 0; r < 16; ++r) {
        const int dcol = hh*32 + (r & 3) + 8*(r >> 2) + 4*hi;
        float val = ((half*2+hh)==0 ? o0[r] : (half*2+hh)==1 ? o1[r]
                     : (half*2+hh)==2 ? o2[r] : o3[r]) * invl;
        *(bf16*)(ow + l31*128 + (((unsigned)(dcol*2)) ^ eswz)) = __float2bfloat16(val);
      }
    }
    #pragma unroll
    for (int m = 0; m < 4; ++m) {
      const int c0 = hi*32 + m*8;
      bf16x8 vv = *(const bf16x8*)(ow + l31*128 + (((unsigned)(c0*2)) ^ eswz));
      *(bf16x8*)(aop + half*64 + c0) = vv;
    }
  }
}

// --------------------------------------------------------------------- launch
extern "C" void kernel_launch(void* const* d_in, const int* in_sizes, int n_in,
                              void* d_out, int out_size, void* d_ws, size_t ws_size,
                              hipStream_t stream)
{
  const float* x    = (const float*)d_in[0];
  const float* cosb = (const float*)d_in[1];
  const float* sinb = (const float*)d_in[2];
  const float* wq   = (const float*)d_in[3];
  const float* wk   = (const float*)d_in[4];
  const float* wv   = (const float*)d_in[5];
  const float* wo   = (const float*)d_in[6];
  const float* qnw  = (const float*)d_in[7];
  const float* knw  = (const float*)d_in[8];
  float* out = (float*)d_out;

  char* ws = (char*)d_ws;
  bf16* xb  = (bf16*)(ws);                  // 32 MiB
  bf16* wqb = (bf16*)(ws +  33554432);      // 32 MiB
  bf16* wkb = (bf16*)(ws +  67108864);      //  8 MiB (contiguous with wvb)
  bf16* wvb = (bf16*)(ws +  75497472);      //  8 MiB
  bf16* wob = (bf16*)(ws +  83886080);      // 32 MiB
  bf16* q0  = (bf16*)(ws + 117440512);      // 32 MiB
  bf16* kv0 = (bf16*)(ws + 150994944);      // 16 MiB [4096][2048] K|V
  bf16* qr  = (bf16*)(ws + 167772160);      // 32 MiB  (end 192 MiB)
  bf16* vt = xb;    // xb dead after QKV GEMMs
  bf16* kr = wqb;   // wqb dead after Q GEMM
  bf16* ao = q0;    // q0 dead after q normrope

  f2b<<<2048, 256, 0, stream>>>(x,  xb,  MR*HH);
  f2b<<<2048, 256, 0, stream>>>(wq, wqb, NH*HD*HH);
  f2b<<<2048, 256, 0, stream>>>(wk, wkb, NKV*HD*HH);
  f2b<<<2048, 256, 0, stream>>>(wv, wvb, NKV*HD*HH);
  f2b<<<2048, 256, 0, stream>>>(wo, wob, HH*NH*HD);

  gemm256<bf16><<<256, 512, 0, stream>>>(xb, wqb, q0,  MR, 4096, HH, 16);
  gemm256<bf16><<<128, 512, 0, stream>>>(xb, wkb, kv0, MR, 2048, HH,  8);

  normrope<<<(MR*NH)/4,  256, 0, stream>>>(q0, qr, cosb, sinb, qnw, NH,
                                           0.08838834764831845f*1.44269504088896341f,
                                           4096, 0);
  normrope<<<(MR*NKV)/4, 256, 0, stream>>>(kv0, kr, cosb, sinb, knw, NKV, 1.0f,
                                           2048, 0);
  vtrans<<<dim3(32, 2, 16), 256, 0, stream>>>(kv0, vt, 2048, 1024);

  attn_fwd<<<512, 512, 0, stream>>>(qr, kr, vt, ao);

  gemm256<float><<<256, 512, 0, stream>>>(ao, wob, out, MR, HH, HH, 16);
}